// Round 1
// baseline (62.790 us; speedup 1.0000x reference)
//
#include <hip/hip_runtime.h>
#include <hip/hip_bf16.h>
#include <math.h>

// Problem constants (match reference setup_inputs)
#define BB 2048
#define CC 1000
#define PP 20

// Kernel 1: one block per row.
//   S_b = sum_j exp(-x[b,j])   (row staged into LDS during the pass)
//   partial[b] = sum_{valid p} ( exp(x[b,t_{b,p}]) * S_b - 1 )
// (since sum_{j != t} exp(x_t - x_j) = exp(x_t)*S_b - exp(x_t)*exp(-x_t)
//                                    = exp(x_t)*S_b - 1)
__global__ __launch_bounds__(256) void lesp_row_kernel(
    const float* __restrict__ x,
    const int* __restrict__ tgt,
    float* __restrict__ partial)
{
    __shared__ float lds_x[CC];
    __shared__ float wave_sums[4];

    const int b = blockIdx.x;
    const float* row = x + (size_t)b * CC;

    // Pass over the row: stage to LDS + accumulate exp(-x)
    float s = 0.0f;
    for (int j = threadIdx.x; j < CC; j += 256) {
        float v = row[j];
        lds_x[j] = v;
        s += __expf(-v);
    }

    // wave (64-lane) shuffle reduction
    for (int off = 32; off > 0; off >>= 1)
        s += __shfl_down(s, off, 64);

    const int wave = threadIdx.x >> 6;
    const int lane = threadIdx.x & 63;
    if (lane == 0) wave_sums[wave] = s;
    __syncthreads();   // also fences lds_x for the gather below

    const float S = wave_sums[0] + wave_sums[1] + wave_sums[2] + wave_sums[3];

    // Lanes 0..19 handle the P targets for this row
    float term = 0.0f;
    if (threadIdx.x < PP) {
        int t = tgt[b * PP + threadIdx.x];
        if (t > -1) {
            float xt = lds_x[t];
            term = __expf(xt) * S - 1.0f;
        }
    }
    // reduce term across wave 0 (lanes >= PP hold 0)
    for (int off = 32; off > 0; off >>= 1)
        term += __shfl_down(term, off, 64);

    if (threadIdx.x == 0) partial[b] = term;
}

// Kernel 2: reduce the 2048 per-row partials, finalize loss.
__global__ __launch_bounds__(256) void lesp_finalize_kernel(
    const float* __restrict__ partial,
    float* __restrict__ out)
{
    __shared__ float wave_sums[4];

    float s = 0.0f;
    for (int i = threadIdx.x; i < BB; i += 256)
        s += partial[i];

    for (int off = 32; off > 0; off >>= 1)
        s += __shfl_down(s, off, 64);

    const int wave = threadIdx.x >> 6;
    const int lane = threadIdx.x & 63;
    if (lane == 0) wave_sums[wave] = s;
    __syncthreads();

    if (threadIdx.x == 0) {
        float total = wave_sums[0] + wave_sums[1] + wave_sums[2] + wave_sums[3];
        out[0] = logf(1.0f + total) / (float)CC;
    }
}

extern "C" void kernel_launch(void* const* d_in, const int* in_sizes, int n_in,
                              void* d_out, int out_size, void* d_ws, size_t ws_size,
                              hipStream_t stream)
{
    const float* x   = (const float*)d_in[0];   // [B, C] fp32
    const int*   tgt = (const int*)d_in[1];     // [B, P] int
    float* out       = (float*)d_out;           // [1] fp32
    float* partial   = (float*)d_ws;            // B floats of scratch

    lesp_row_kernel<<<BB, 256, 0, stream>>>(x, tgt, partial);
    lesp_finalize_kernel<<<1, 256, 0, stream>>>(partial, out);
}